// Round 13
// baseline (1887.699 us; speedup 1.0000x reference)
//
#include <hip/hip_runtime.h>

#define NB 4
#define CC 64
#define HW 4096
#define NT (NB*HW)
#define EPSV 1e-5f
#define LOG2E 1.4426950408889634f

typedef _Float16 f16;
typedef _Float16 half4 __attribute__((ext_vector_type(4)));
typedef _Float16 half8 __attribute__((ext_vector_type(8)));
typedef float   float4v __attribute__((ext_vector_type(4)));

#define NELEM ((size_t)NB*HW*CC)   // 1,048,576 per tensor
#define NSLOT 128                  // conv2 partial-stat slots (NB * HW/128)

// ws: fp32 [512..512+NSLOT*256): per-(n,bx) partial BN stats.
// Byte 264192+: f16 q, k ([n][hw][c]) and gv ([n][c][hw]) — 3 x 2 MB.
#define PART_OFF 512
#define TEN_OFF  264192

// ---------------------------------------------------------------------------
// conv2: 3 fused 1x1 convs; 128 px/block (2 adjacent px per thread), 4-way
// channel split over blockIdx.z. grid (HW/128, NB, 4), 256 thr. (r12, kept)
// ---------------------------------------------------------------------------
__global__ __launch_bounds__(256)
void conv2_kernel(const float* __restrict__ x,
                  const float* __restrict__ h0, const float* __restrict__ h1,
                  const float* __restrict__ Wq, const float* __restrict__ bq,
                  const float* __restrict__ Wk, const float* __restrict__ bk,
                  const float* __restrict__ Wv, const float* __restrict__ bv,
                  float* __restrict__ ws,
                  f16* __restrict__ q, f16* __restrict__ k, f16* __restrict__ gv)
{
    __shared__ float Wl[3][16*CC];   // 12 KB
    __shared__ float xs[CC][128];    // 32 KB
    const int t    = threadIdx.x;
    const int n    = blockIdx.y;
    const int z    = blockIdx.z;
    const int px0  = blockIdx.x * 128;
    const int lane = t & 63;
    const int grp  = t >> 6;
    const int ocl  = grp * 4;
    const int oc0  = z*16 + ocl;

    ((float4*)Wl[0])[t] = ((const float4*)(Wq + (size_t)z*16*CC))[t];
    ((float4*)Wl[1])[t] = ((const float4*)(Wk + (size_t)z*16*CC))[t];
    ((float4*)Wl[2])[t] = ((const float4*)(Wv + (size_t)z*16*CC))[t];
    for (int i = t; i < CC*32; i += 256) {          // 2048 float4
        int ic = i >> 5, c4 = i & 31;
        ((float4*)&xs[ic][0])[c4] =
            ((const float4*)(x + ((size_t)n*CC + ic)*HW + px0))[c4];
    }
    __syncthreads();

    float aq[4][2], ak[4][2], av[4][2];
    #pragma unroll
    for (int j = 0; j < 4; ++j) {
        aq[j][0] = aq[j][1] = bq[oc0+j];
        ak[j][0] = ak[j][1] = bk[oc0+j];
        av[j][0] = av[j][1] = bv[oc0+j];
    }

    for (int ic = 0; ic < CC; ic += 4) {
        float2 xv0 = *(float2*)&xs[ic  ][lane*2];
        float2 xv1 = *(float2*)&xs[ic+1][lane*2];
        float2 xv2 = *(float2*)&xs[ic+2][lane*2];
        float2 xv3 = *(float2*)&xs[ic+3][lane*2];
        #pragma unroll
        for (int j = 0; j < 4; ++j) {
            const int row = (ocl+j)*CC + ic;
            float4 wq = *(const float4*)&Wl[0][row];
            float4 wk = *(const float4*)&Wl[1][row];
            float4 wv = *(const float4*)&Wl[2][row];
            aq[j][0] = fmaf(wq.x,xv0.x, fmaf(wq.y,xv1.x, fmaf(wq.z,xv2.x, fmaf(wq.w,xv3.x, aq[j][0]))));
            aq[j][1] = fmaf(wq.x,xv0.y, fmaf(wq.y,xv1.y, fmaf(wq.z,xv2.y, fmaf(wq.w,xv3.y, aq[j][1]))));
            ak[j][0] = fmaf(wk.x,xv0.x, fmaf(wk.y,xv1.x, fmaf(wk.z,xv2.x, fmaf(wk.w,xv3.x, ak[j][0]))));
            ak[j][1] = fmaf(wk.x,xv0.y, fmaf(wk.y,xv1.y, fmaf(wk.z,xv2.y, fmaf(wk.w,xv3.y, ak[j][1]))));
            av[j][0] = fmaf(wv.x,xv0.x, fmaf(wv.y,xv1.x, fmaf(wv.z,xv2.x, fmaf(wv.w,xv3.x, av[j][0]))));
            av[j][1] = fmaf(wv.x,xv0.y, fmaf(wv.y,xv1.y, fmaf(wv.z,xv2.y, fmaf(wv.w,xv3.y, av[j][1]))));
        }
    }

    const int px = px0 + lane*2;
    const size_t base = ((size_t)n*HW + px)*CC + oc0;
    half4 vq0, vq1, vk0, vk1;
    #pragma unroll
    for (int j = 0; j < 4; ++j) {
        vq0[j] = (f16)aq[j][0]; vq1[j] = (f16)aq[j][1];
        vk0[j] = (f16)ak[j][0]; vk1[j] = (f16)ak[j][1];
    }
    *(half4*)&q[base]      = vq0;  *(half4*)&q[base + CC] = vq1;
    *(half4*)&k[base]      = vk0;  *(half4*)&k[base + CC] = vk1;

    #pragma unroll
    for (int j = 0; j < 4; ++j) {
        size_t gi = ((size_t)n*CC + oc0 + j)*HW + px;
        f16 g0 = (f16)((h0[gi]   + h1[gi]  ) * av[j][0]);
        f16 g1 = (f16)((h0[gi+1] + h1[gi+1]) * av[j][1]);
        gv[gi]   = g0;
        gv[gi+1] = g1;
    }

    float* slot = ws + PART_OFF + (size_t)(n*(HW/128) + blockIdx.x)*256;
    #pragma unroll
    for (int j = 0; j < 4; ++j) {
        float v0 = aq[j][0] + aq[j][1];
        float v1 = aq[j][0]*aq[j][0] + aq[j][1]*aq[j][1];
        float v2 = ak[j][0] + ak[j][1];
        float v3 = ak[j][0]*ak[j][0] + ak[j][1]*ak[j][1];
        #pragma unroll
        for (int off = 32; off > 0; off >>= 1) {
            v0 += __shfl_down(v0, off);
            v1 += __shfl_down(v1, off);
            v2 += __shfl_down(v2, off);
            v3 += __shfl_down(v3, off);
        }
        if (lane == 0) {
            slot[      oc0 + j] = v0;
            slot[ 64 + oc0 + j] = v1;
            slot[128 + oc0 + j] = v2;
            slot[192 + oc0 + j] = v3;
        }
    }
}

// ---------------------------------------------------------------------------
// apply: folds BN stats redundantly per block, then y = relu(s*y+t) in place,
// 16 f16/thread. blockIdx.y: 0=q, 1=k (k pre-scaled by log2e). (r12, kept)
// ---------------------------------------------------------------------------
__global__ __launch_bounds__(256)
void apply_kernel(f16* __restrict__ q, f16* __restrict__ k,
                  const float* __restrict__ ws,
                  const float* __restrict__ gq, const float* __restrict__ betaq,
                  const float* __restrict__ gk, const float* __restrict__ betak)
{
    __shared__ float tot[128];
    __shared__ float sc[CC], sh[CC];
    const int t = threadIdx.x;
    const int tens = blockIdx.y;

    if (t < 128) {
        const float* base = ws + PART_OFF + tens*128 + t;
        float acc = 0.0f;
        #pragma unroll 8
        for (int s = 0; s < NSLOT; ++s) acc += base[(size_t)s*256];
        tot[t] = acc;
    }
    __syncthreads();
    if (t < 64) {
        float mean = tot[t] * (1.0f / NT);
        float var  = tot[64 + t] * (1.0f / NT) - mean*mean;
        if (tens == 0) {
            float s = gq[t] * rsqrtf(var + EPSV);
            sc[t] = s;  sh[t] = betaq[t] - mean*s;
        } else {
            float s = gk[t] * rsqrtf(var + EPSV);
            sc[t] = s * LOG2E;  sh[t] = (betak[t] - mean*s) * LOG2E;
        }
    }
    __syncthreads();

    f16* p = tens ? k : q;
    const size_t e0 = ((size_t)blockIdx.x * 256 + t) * 16;
    const int c0 = (int)(e0 & 63);

    half8 v0 = *(half8*)&p[e0], v1 = *(half8*)&p[e0 + 8];
    half8 o0, o1;
    #pragma unroll
    for (int j = 0; j < 8; ++j) {
        o0[j] = (f16)fmaxf(fmaf(sc[c0+j],   (float)v0[j], sh[c0+j]),   0.0f);
        o1[j] = (f16)fmaxf(fmaf(sc[c0+8+j], (float)v1[j], sh[c0+8+j]), 0.0f);
    }
    *(half8*)&p[e0]     = o0;
    *(half8*)&p[e0 + 8] = o1;
}

// ---------------------------------------------------------------------------
// MFMA flash attention, S^T form, stale-max exact softmax — SPILL-FREE rework
// of r12: exp2 overwrites accS IN PLACE (p and accS never co-live; r12 kept
// both -> 194 MB scratch spills -> 1850 µs). Fast path: no cross-lane ops,
// per-lane overflow guard (pmax > 2^15). Rare wave-uniform fixup recovers the
// row max FROM P (mn = m + max(log2(rowpmax),0), al = exp2(m-mn)); any al is
// self-consistent (cancels in O = sum pV / sum p) so log2 rounding is safe.
// PV + l use 16x16x32 MFMAs (key-slot order: lo=tile0, hi=tile1 per quad).
// grid (HW/64, NB) = 256 blocks, 512 thr; wave w owns keys [w*512,+512).
// Layout (validated r4-r12): mfma(X,Y) -> D[p=quad*4+reg <- X row][q=lane&15 <- Y row].
// ---------------------------------------------------------------------------
__global__ __launch_bounds__(512, 2)
void attn_kernel(const f16* __restrict__ q, const f16* __restrict__ k,
                 const f16* __restrict__ gv, float* __restrict__ out)
{
    __shared__ float Obuf[8][4][256];   // [wave][ct][lane*4] — 32 KB, reused 4x
    __shared__ float MLbuf[2][8][64];   // [m|l][wave][qrow]  — 4 KB

    const int t    = threadIdx.x;
    const int n    = blockIdx.y;
    const int w    = t >> 6;
    const int lane = t & 63;
    const int m16  = lane & 15;
    const int kb   = lane >> 4;
    const int q0   = blockIdx.x * 64;

    half8 qf[4][2];
    #pragma unroll
    for (int qt = 0; qt < 4; ++qt) {
        const size_t qb = ((size_t)n*HW + q0 + qt*16 + m16)*CC + kb*8;
        qf[qt][0] = *(const half8*)&q[qb];
        qf[qt][1] = *(const half8*)&q[qb + 32];
    }

    const int    kt0   = w * 512;
    const size_t krow  = (size_t)n*HW*CC;
    const size_t gbase = ((size_t)n*CC + m16)*HW;

    half8 khf[2][2][2];   // [buf][ktile][chalf]
    half8 gvf[2][4];      // [buf][ct] — slots lo = key tile0, hi = key tile1
    half8 ones8;
    #pragma unroll
    for (int j = 0; j < 8; ++j) ones8[j] = (f16)1.f;

#define LOADK(B, KT) do {                                                     \
    size_t a_ = krow + ((size_t)(KT) + m16)*CC + kb*8;                        \
    khf[B][0][0] = *(const half8*)&k[a_];                                     \
    khf[B][0][1] = *(const half8*)&k[a_ + 32];                                \
    khf[B][1][0] = *(const half8*)&k[a_ + 16*CC];                             \
    khf[B][1][1] = *(const half8*)&k[a_ + 16*CC + 32];                        \
} while (0)

#define LOADGV(B, KT) do {                                                    \
    size_t g_ = gbase + (size_t)(KT) + kb*4;                                  \
    _Pragma("unroll") for (int ct_ = 0; ct_ < 4; ++ct_) {                     \
        half4 a_ = *(const half4*)&gv[g_ + (size_t)ct_*16*HW];                \
        half4 b_ = *(const half4*)&gv[g_ + 16 + (size_t)ct_*16*HW];           \
        _Pragma("unroll") for (int j_ = 0; j_ < 4; ++j_) {                    \
            gvf[B][ct_][j_]   = a_[j_];                                       \
            gvf[B][ct_][4+j_] = b_[j_];                                       \
        }                                                                     \
    }                                                                         \
} while (0)

#define SMFMA(B, accS) do {                                                   \
    _Pragma("unroll") for (int qt_ = 0; qt_ < 4; ++qt_)                       \
    _Pragma("unroll") for (int k2_ = 0; k2_ < 2; ++k2_) {                     \
        float4v z_ = {0.f,0.f,0.f,0.f};                                       \
        z_ = __builtin_amdgcn_mfma_f32_16x16x32_f16(khf[B][k2_][0], qf[qt_][0], z_, 0,0,0); \
        accS[qt_][k2_] = __builtin_amdgcn_mfma_f32_16x16x32_f16(khf[B][k2_][1], qf[qt_][1], z_, 0,0,0); \
    }                                                                         \
} while (0)

// pack p (stored in accS) and run accL/PV with 16x16x32
#define PACK_PV(B, P) do {                                                    \
    _Pragma("unroll") for (int qt_ = 0; qt_ < 4; ++qt_) {                     \
        half8 pf8;                                                            \
        _Pragma("unroll") for (int e_ = 0; e_ < 4; ++e_) {                    \
            pf8[e_]   = (f16)P[qt_][0][e_];                                   \
            pf8[4+e_] = (f16)P[qt_][1][e_];                                   \
        }                                                                     \
        accL[qt_] = __builtin_amdgcn_mfma_f32_16x16x32_f16(ones8, pf8, accL[qt_], 0,0,0); \
        _Pragma("unroll") for (int ct_ = 0; ct_ < 4; ++ct_)                   \
            accO[qt_][ct_] = __builtin_amdgcn_mfma_f32_16x16x32_f16(gvf[B][ct_], pf8, accO[qt_][ct_], 0,0,0); \
    }                                                                         \
} while (0)

    float4v accO[4][4], accL[4];
    #pragma unroll
    for (int qt = 0; qt < 4; ++qt) {
        #pragma unroll
        for (int ct = 0; ct < 4; ++ct) accO[qt][ct] = (float4v){0.f,0.f,0.f,0.f};
        accL[qt] = (float4v){0.f,0.f,0.f,0.f};
    }
    float m[4];

    // ---- prologue (step 0): true tree init of m; exp2 in place; PV
    LOADK(0, kt0);
    LOADGV(0, kt0);
    {
        float4v accS[4][2];
        SMFMA(0, accS);
        LOADK(1, kt0 + 32);
        LOADGV(1, kt0 + 32);
        #pragma unroll
        for (int qt = 0; qt < 4; ++qt) {
            float mx = fmaxf(fmaxf(fmaxf(accS[qt][0][0], accS[qt][0][1]),
                                   fmaxf(accS[qt][0][2], accS[qt][0][3])),
                             fmaxf(fmaxf(accS[qt][1][0], accS[qt][1][1]),
                                   fmaxf(accS[qt][1][2], accS[qt][1][3])));
            mx = fmaxf(mx, __shfl_xor(mx, 16));
            mx = fmaxf(mx, __shfl_xor(mx, 32));
            m[qt] = mx;
            #pragma unroll
            for (int e = 0; e < 4; ++e) {
                accS[qt][0][e] = exp2f(accS[qt][0][e] - mx);
                accS[qt][1][e] = exp2f(accS[qt][1][e] - mx);
            }
        }
        PACK_PV(0, accS);
    }

    // ---- fast steps 1..15: stale-max, in-place p, no cross-lane ops
    for (int it = 1; it < 16; ++it) {
        const int B = it & 1;
        LOADK(1-B, kt0 + (it+1)*32);   // it=15 overreads ws slack: unused
        LOADGV(1-B, kt0 + (it+1)*32);
        float4v accS[4][2];
        SMFMA(B, accS);

        float pmax4[4];
        float pmax = 0.0f;
        #pragma unroll
        for (int qt = 0; qt < 4; ++qt) {
            #pragma unroll
            for (int e = 0; e < 4; ++e) {
                accS[qt][0][e] = exp2f(accS[qt][0][e] - m[qt]);
                accS[qt][1][e] = exp2f(accS[qt][1][e] - m[qt]);
            }
            float pm = fmaxf(fmaxf(fmaxf(accS[qt][0][0], accS[qt][0][1]),
                                   fmaxf(accS[qt][0][2], accS[qt][0][3])),
                             fmaxf(fmaxf(accS[qt][1][0], accS[qt][1][1]),
                                   fmaxf(accS[qt][1][2], accS[qt][1][3])));
            pmax4[qt] = pm;
            pmax = fmaxf(pmax, pm);
        }

        if (__any(pmax > 32768.0f)) {      // rare: f16-pack overflow risk
            #pragma unroll
            for (int qt = 0; qt < 4; ++qt) {
                float pm = pmax4[qt];
                pm = fmaxf(pm, __shfl_xor(pm, 16));
                pm = fmaxf(pm, __shfl_xor(pm, 32));
                float mn = m[qt] + fmaxf(log2f(pm), 0.0f);   // only raise
                float al = exp2f(m[qt] - mn);                // consistent factor
                m[qt] = mn;
                #pragma unroll
                for (int e = 0; e < 4; ++e) {
                    accS[qt][0][e] *= al;
                    accS[qt][1][e] *= al;
                }
                accL[qt][0] *= al;   // only [0] is ever read
                #pragma unroll
                for (int ct = 0; ct < 4; ++ct) {
                    accO[qt][ct][0]*=al; accO[qt][ct][1]*=al;
                    accO[qt][ct][2]*=al; accO[qt][ct][3]*=al;
                }
            }
        }
        PACK_PV(B, accS);
    }

    // publish (m, l) per q-row — accL[0] holds the full cross-quad row sum
    if (kb == 0) {
        #pragma unroll
        for (int qt = 0; qt < 4; ++qt) {
            MLbuf[0][w][qt*16 + m16] = m[qt];
            MLbuf[1][w][qt*16 + m16] = accL[qt][0];
        }
    }
    __syncthreads();

    // global M, L per q-row; scale own partials into the shared frame
    float invL[4];
    #pragma unroll
    for (int qt = 0; qt < 4; ++qt) {
        const int r = qt*16 + m16;
        float M = MLbuf[0][0][r];
        #pragma unroll
        for (int src = 1; src < 8; ++src) M = fmaxf(M, MLbuf[0][src][r]);
        float L = 0.0f;
        #pragma unroll
        for (int src = 0; src < 8; ++src)
            L += MLbuf[1][src][r] * exp2f(MLbuf[0][src][r] - M);
        const float f = exp2f(m[qt] - M);
        #pragma unroll
        for (int ct = 0; ct < 4; ++ct) {
            accO[qt][ct][0] *= f; accO[qt][ct][1] *= f;
            accO[qt][ct][2] *= f; accO[qt][ct][3] *= f;
        }
        invL[qt] = 1.0f / L;
    }

    // 4 staged merge rounds: round rd handles q-tile rd
    for (int rd = 0; rd < 4; ++rd) {
        __syncthreads();
        #pragma unroll
        for (int ct = 0; ct < 4; ++ct)
            ((float4*)&Obuf[w][ct][0])[lane] =
                (float4){accO[rd][ct][0], accO[rd][ct][1], accO[rd][ct][2], accO[rd][ct][3]};
        __syncthreads();
        if (w < 4) {
            float4 s = ((float4*)&Obuf[0][w][0])[lane];
            #pragma unroll
            for (int src = 1; src < 8; ++src) {
                float4 v = ((float4*)&Obuf[src][w][0])[lane];
                s.x += v.x; s.y += v.y; s.z += v.z; s.w += v.w;
            }
            const float iv = invL[rd];
            const int chb = w*16 + kb*4;
            const int row = q0 + rd*16 + m16;
            out[((size_t)n*CC + chb + 0)*HW + row] = s.x * iv;
            out[((size_t)n*CC + chb + 1)*HW + row] = s.y * iv;
            out[((size_t)n*CC + chb + 2)*HW + row] = s.z * iv;
            out[((size_t)n*CC + chb + 3)*HW + row] = s.w * iv;
        }
    }
#undef PACK_PV
#undef SMFMA
#undef LOADGV
#undef LOADK
}

// ---------------------------------------------------------------------------
extern "C" void kernel_launch(void* const* d_in, const int* in_sizes, int n_in,
                              void* d_out, int out_size, void* d_ws, size_t ws_size,
                              hipStream_t stream)
{
    const float* low   = (const float*)d_in[0];
    const float* h0    = (const float*)d_in[1];
    const float* h1    = (const float*)d_in[2];
    const float* Wq    = (const float*)d_in[3];
    const float* bq    = (const float*)d_in[4];
    const float* gq    = (const float*)d_in[5];
    const float* betaq = (const float*)d_in[6];
    const float* Wk    = (const float*)d_in[7];
    const float* bk    = (const float*)d_in[8];
    const float* gk    = (const float*)d_in[9];
    const float* betak = (const float*)d_in[10];
    const float* Wv    = (const float*)d_in[11];
    const float* bv    = (const float*)d_in[12];

    float* wsf = (float*)d_ws;
    float* out = (float*)d_out;

    f16* q  = (f16*)((char*)d_ws + TEN_OFF);
    f16* k  = q + NELEM;
    f16* gv = k + NELEM;

    conv2_kernel<<<dim3(HW/128, NB, 4), 256, 0, stream>>>(
        low, h0, h1, Wq, bq, Wk, bk, Wv, bv, wsf, q, k, gv);

    apply_kernel<<<dim3((int)(NELEM/(256*16)), 2), 256, 0, stream>>>(
        q, k, wsf, gq, betaq, gk, betak);

    attn_kernel<<<dim3(HW/64, NB), 512, 0, stream>>>(q, k, gv, out);
}

// Round 14
// 155.176 us; speedup vs baseline: 12.1649x; 12.1649x over previous
//
#include <hip/hip_runtime.h>

#define NB 4
#define CC 64
#define HW 4096
#define NT (NB*HW)
#define EPSV 1e-5f
#define LOG2E 1.4426950408889634f

typedef _Float16 f16;
typedef _Float16 half4 __attribute__((ext_vector_type(4)));
typedef _Float16 half8 __attribute__((ext_vector_type(8)));
typedef float   float4v __attribute__((ext_vector_type(4)));

#define NELEM ((size_t)NB*HW*CC)   // 1,048,576 per tensor
#define NSLOT 128                  // conv2 partial-stat slots (NB * HW/128)

// ws: fp32 [512..512+NSLOT*256): per-(n,bx) partial BN stats.
// Byte 264192+: f16 q, k ([n][hw][c]) and gv ([n][c][hw]) — 3 x 2 MB.
#define PART_OFF 512
#define TEN_OFF  264192

// ---------------------------------------------------------------------------
// conv2: 3 fused 1x1 convs; 128 px/block (2 adjacent px per thread), 4-way
// channel split over blockIdx.z. grid (HW/128, NB, 4), 256 thr. (r12, kept —
// measured: non-attn pipeline total ~36 µs)
// ---------------------------------------------------------------------------
__global__ __launch_bounds__(256)
void conv2_kernel(const float* __restrict__ x,
                  const float* __restrict__ h0, const float* __restrict__ h1,
                  const float* __restrict__ Wq, const float* __restrict__ bq,
                  const float* __restrict__ Wk, const float* __restrict__ bk,
                  const float* __restrict__ Wv, const float* __restrict__ bv,
                  float* __restrict__ ws,
                  f16* __restrict__ q, f16* __restrict__ k, f16* __restrict__ gv)
{
    __shared__ float Wl[3][16*CC];   // 12 KB
    __shared__ float xs[CC][128];    // 32 KB
    const int t    = threadIdx.x;
    const int n    = blockIdx.y;
    const int z    = blockIdx.z;
    const int px0  = blockIdx.x * 128;
    const int lane = t & 63;
    const int grp  = t >> 6;
    const int ocl  = grp * 4;
    const int oc0  = z*16 + ocl;

    ((float4*)Wl[0])[t] = ((const float4*)(Wq + (size_t)z*16*CC))[t];
    ((float4*)Wl[1])[t] = ((const float4*)(Wk + (size_t)z*16*CC))[t];
    ((float4*)Wl[2])[t] = ((const float4*)(Wv + (size_t)z*16*CC))[t];
    for (int i = t; i < CC*32; i += 256) {          // 2048 float4
        int ic = i >> 5, c4 = i & 31;
        ((float4*)&xs[ic][0])[c4] =
            ((const float4*)(x + ((size_t)n*CC + ic)*HW + px0))[c4];
    }
    __syncthreads();

    float aq[4][2], ak[4][2], av[4][2];
    #pragma unroll
    for (int j = 0; j < 4; ++j) {
        aq[j][0] = aq[j][1] = bq[oc0+j];
        ak[j][0] = ak[j][1] = bk[oc0+j];
        av[j][0] = av[j][1] = bv[oc0+j];
    }

    for (int ic = 0; ic < CC; ic += 4) {
        float2 xv0 = *(float2*)&xs[ic  ][lane*2];
        float2 xv1 = *(float2*)&xs[ic+1][lane*2];
        float2 xv2 = *(float2*)&xs[ic+2][lane*2];
        float2 xv3 = *(float2*)&xs[ic+3][lane*2];
        #pragma unroll
        for (int j = 0; j < 4; ++j) {
            const int row = (ocl+j)*CC + ic;
            float4 wq = *(const float4*)&Wl[0][row];
            float4 wk = *(const float4*)&Wl[1][row];
            float4 wv = *(const float4*)&Wl[2][row];
            aq[j][0] = fmaf(wq.x,xv0.x, fmaf(wq.y,xv1.x, fmaf(wq.z,xv2.x, fmaf(wq.w,xv3.x, aq[j][0]))));
            aq[j][1] = fmaf(wq.x,xv0.y, fmaf(wq.y,xv1.y, fmaf(wq.z,xv2.y, fmaf(wq.w,xv3.y, aq[j][1]))));
            ak[j][0] = fmaf(wk.x,xv0.x, fmaf(wk.y,xv1.x, fmaf(wk.z,xv2.x, fmaf(wk.w,xv3.x, ak[j][0]))));
            ak[j][1] = fmaf(wk.x,xv0.y, fmaf(wk.y,xv1.y, fmaf(wk.z,xv2.y, fmaf(wk.w,xv3.y, ak[j][1]))));
            av[j][0] = fmaf(wv.x,xv0.x, fmaf(wv.y,xv1.x, fmaf(wv.z,xv2.x, fmaf(wv.w,xv3.x, av[j][0]))));
            av[j][1] = fmaf(wv.x,xv0.y, fmaf(wv.y,xv1.y, fmaf(wv.z,xv2.y, fmaf(wv.w,xv3.y, av[j][1]))));
        }
    }

    const int px = px0 + lane*2;
    const size_t base = ((size_t)n*HW + px)*CC + oc0;
    half4 vq0, vq1, vk0, vk1;
    #pragma unroll
    for (int j = 0; j < 4; ++j) {
        vq0[j] = (f16)aq[j][0]; vq1[j] = (f16)aq[j][1];
        vk0[j] = (f16)ak[j][0]; vk1[j] = (f16)ak[j][1];
    }
    *(half4*)&q[base]      = vq0;  *(half4*)&q[base + CC] = vq1;
    *(half4*)&k[base]      = vk0;  *(half4*)&k[base + CC] = vk1;

    #pragma unroll
    for (int j = 0; j < 4; ++j) {
        size_t gi = ((size_t)n*CC + oc0 + j)*HW + px;
        f16 g0 = (f16)((h0[gi]   + h1[gi]  ) * av[j][0]);
        f16 g1 = (f16)((h0[gi+1] + h1[gi+1]) * av[j][1]);
        gv[gi]   = g0;
        gv[gi+1] = g1;
    }

    float* slot = ws + PART_OFF + (size_t)(n*(HW/128) + blockIdx.x)*256;
    #pragma unroll
    for (int j = 0; j < 4; ++j) {
        float v0 = aq[j][0] + aq[j][1];
        float v1 = aq[j][0]*aq[j][0] + aq[j][1]*aq[j][1];
        float v2 = ak[j][0] + ak[j][1];
        float v3 = ak[j][0]*ak[j][0] + ak[j][1]*ak[j][1];
        #pragma unroll
        for (int off = 32; off > 0; off >>= 1) {
            v0 += __shfl_down(v0, off);
            v1 += __shfl_down(v1, off);
            v2 += __shfl_down(v2, off);
            v3 += __shfl_down(v3, off);
        }
        if (lane == 0) {
            slot[      oc0 + j] = v0;
            slot[ 64 + oc0 + j] = v1;
            slot[128 + oc0 + j] = v2;
            slot[192 + oc0 + j] = v3;
        }
    }
}

// ---------------------------------------------------------------------------
// apply: folds BN stats redundantly per block, then y = relu(s*y+t) in place,
// 16 f16/thread. blockIdx.y: 0=q, 1=k (k pre-scaled by log2e). (r12, kept)
// ---------------------------------------------------------------------------
__global__ __launch_bounds__(256)
void apply_kernel(f16* __restrict__ q, f16* __restrict__ k,
                  const float* __restrict__ ws,
                  const float* __restrict__ gq, const float* __restrict__ betaq,
                  const float* __restrict__ gk, const float* __restrict__ betak)
{
    __shared__ float tot[128];
    __shared__ float sc[CC], sh[CC];
    const int t = threadIdx.x;
    const int tens = blockIdx.y;

    if (t < 128) {
        const float* base = ws + PART_OFF + tens*128 + t;
        float acc = 0.0f;
        #pragma unroll 8
        for (int s = 0; s < NSLOT; ++s) acc += base[(size_t)s*256];
        tot[t] = acc;
    }
    __syncthreads();
    if (t < 64) {
        float mean = tot[t] * (1.0f / NT);
        float var  = tot[64 + t] * (1.0f / NT) - mean*mean;
        if (tens == 0) {
            float s = gq[t] * rsqrtf(var + EPSV);
            sc[t] = s;  sh[t] = betaq[t] - mean*s;
        } else {
            float s = gk[t] * rsqrtf(var + EPSV);
            sc[t] = s * LOG2E;  sh[t] = (betak[t] - mean*s) * LOG2E;
        }
    }
    __syncthreads();

    f16* p = tens ? k : q;
    const size_t e0 = ((size_t)blockIdx.x * 256 + t) * 16;
    const int c0 = (int)(e0 & 63);

    half8 v0 = *(half8*)&p[e0], v1 = *(half8*)&p[e0 + 8];
    half8 o0, o1;
    #pragma unroll
    for (int j = 0; j < 8; ++j) {
        o0[j] = (f16)fmaxf(fmaf(sc[c0+j],   (float)v0[j], sh[c0+j]),   0.0f);
        o1[j] = (f16)fmaxf(fmaf(sc[c0+8+j], (float)v1[j], sh[c0+8+j]), 0.0f);
    }
    *(half8*)&p[e0]     = o0;
    *(half8*)&p[e0 + 8] = o1;
}

// ---------------------------------------------------------------------------
// MFMA flash attention — VERBATIM r11 (measured: 59.8 µs, VGPR 116, zero
// scratch). Exact online softmax with lazy rescale (wave-uniform __any guard);
// l via ones-operand 16x16x16 MFMA; PV via 16x16x16 half4 fragments.
// r12's 16x16x32 PV restructure (permuted gvf half8 packing) triggered ~190 MB
// of scratch spills (MfmaUtil 0.4%, 1850 µs) in both r12 and r13 variants —
// do NOT reintroduce it without -Rpass spill evidence.
// grid (HW/64, NB) = 256 blocks, 512 thr; wave w owns keys [w*512,+512).
// Layout (validated r4-r11): mfma(X,Y) -> D[p=quad*4+reg <- X row][q=lane&15 <- Y row].
// ---------------------------------------------------------------------------
__global__ __launch_bounds__(512, 2)
void attn_kernel(const f16* __restrict__ q, const f16* __restrict__ k,
                 const f16* __restrict__ gv, float* __restrict__ out)
{
    __shared__ float Obuf[8][4][256];   // [wave][ct][lane*4] — 32 KB, reused 4x
    __shared__ float MLbuf[2][8][64];   // [m|l][wave][qrow]  — 4 KB

    const int t    = threadIdx.x;
    const int n    = blockIdx.y;
    const int w    = t >> 6;
    const int lane = t & 63;
    const int m16  = lane & 15;
    const int kb   = lane >> 4;
    const int q0   = blockIdx.x * 64;

    half8 qf[4][2];
    #pragma unroll
    for (int qt = 0; qt < 4; ++qt) {
        const size_t qb = ((size_t)n*HW + q0 + qt*16 + m16)*CC + kb*8;
        qf[qt][0] = *(const half8*)&q[qb];
        qf[qt][1] = *(const half8*)&q[qb + 32];
    }

    const int    kt0   = w * 512;
    const size_t krow  = (size_t)n*HW*CC;
    const size_t gbase = ((size_t)n*CC + m16)*HW;

    half8 khf[2][2][2];     // [buf][ktile][chalf]
    half4 gvf[2][2][4];     // [buf][ktile][ct]
    const half4 ones = {(f16)1.f, (f16)1.f, (f16)1.f, (f16)1.f};

#define LOADK(B, KT) do {                                                     \
    size_t a_ = krow + ((size_t)(KT) + m16)*CC + kb*8;                        \
    khf[B][0][0] = *(const half8*)&k[a_];                                     \
    khf[B][0][1] = *(const half8*)&k[a_ + 32];                                \
    khf[B][1][0] = *(const half8*)&k[a_ + 16*CC];                             \
    khf[B][1][1] = *(const half8*)&k[a_ + 16*CC + 32];                        \
} while (0)

#define LOADGV(B, KT) do {                                                    \
    size_t g_ = gbase + (size_t)(KT) + kb*4;                                  \
    _Pragma("unroll") for (int k2_ = 0; k2_ < 2; ++k2_)                       \
    _Pragma("unroll") for (int ct_ = 0; ct_ < 4; ++ct_)                       \
        gvf[B][k2_][ct_] = *(const half4*)&gv[g_ + k2_*16 + (size_t)ct_*16*HW];\
} while (0)

    float4v accO[4][4], accL[4];
    #pragma unroll
    for (int qt = 0; qt < 4; ++qt) {
        #pragma unroll
        for (int ct = 0; ct < 4; ++ct) accO[qt][ct] = (float4v){0.f,0.f,0.f,0.f};
        accL[qt] = (float4v){0.f,0.f,0.f,0.f};
    }
    float m[4] = {-INFINITY,-INFINITY,-INFINITY,-INFINITY};

#define STEP(B, NB_, KTN) do {                                                \
    LOADK(NB_, KTN);                                                          \
    LOADGV(NB_, KTN);                                                         \
    float4v accS[4][2];                                                       \
    _Pragma("unroll") for (int qt_ = 0; qt_ < 4; ++qt_)                       \
    _Pragma("unroll") for (int k2_ = 0; k2_ < 2; ++k2_) {                     \
        float4v z_ = {0.f,0.f,0.f,0.f};                                       \
        z_ = __builtin_amdgcn_mfma_f32_16x16x32_f16(khf[B][k2_][0], qf[qt_][0], z_, 0,0,0); \
        accS[qt_][k2_] = __builtin_amdgcn_mfma_f32_16x16x32_f16(khf[B][k2_][1], qf[qt_][1], z_, 0,0,0); \
    }                                                                         \
    float mx[4];                                                              \
    _Pragma("unroll") for (int qt_ = 0; qt_ < 4; ++qt_) {                     \
        float v_ = fmaxf(fmaxf(fmaxf(accS[qt_][0][0], accS[qt_][0][1]),       \
                               fmaxf(accS[qt_][0][2], accS[qt_][0][3])),      \
                         fmaxf(fmaxf(accS[qt_][1][0], accS[qt_][1][1]),       \
                               fmaxf(accS[qt_][1][2], accS[qt_][1][3])));     \
        v_ = fmaxf(v_, __shfl_xor(v_, 16));                                   \
        v_ = fmaxf(v_, __shfl_xor(v_, 32));                                   \
        mx[qt_] = v_;                                                         \
    }                                                                         \
    int need_ = (mx[0] > m[0]) | (mx[1] > m[1]) |                             \
                (mx[2] > m[2]) | (mx[3] > m[3]);                              \
    if (__any(need_)) {                                                       \
        _Pragma("unroll") for (int qt_ = 0; qt_ < 4; ++qt_) {                 \
            float mn_ = fmaxf(m[qt_], mx[qt_]);                               \
            float al_ = exp2f(m[qt_] - mn_);                                  \
            m[qt_] = mn_;                                                     \
            accL[qt_][0]*=al_; accL[qt_][1]*=al_;                             \
            accL[qt_][2]*=al_; accL[qt_][3]*=al_;                             \
            _Pragma("unroll") for (int ct_ = 0; ct_ < 4; ++ct_) {             \
                accO[qt_][ct_][0]*=al_; accO[qt_][ct_][1]*=al_;               \
                accO[qt_][ct_][2]*=al_; accO[qt_][ct_][3]*=al_;               \
            }                                                                 \
        }                                                                     \
    }                                                                         \
    _Pragma("unroll") for (int qt_ = 0; qt_ < 4; ++qt_) {                     \
        float p0 = exp2f(accS[qt_][0][0]-m[qt_]), p1 = exp2f(accS[qt_][0][1]-m[qt_]); \
        float p2 = exp2f(accS[qt_][0][2]-m[qt_]), p3 = exp2f(accS[qt_][0][3]-m[qt_]); \
        float p4 = exp2f(accS[qt_][1][0]-m[qt_]), p5 = exp2f(accS[qt_][1][1]-m[qt_]); \
        float p6 = exp2f(accS[qt_][1][2]-m[qt_]), p7 = exp2f(accS[qt_][1][3]-m[qt_]); \
        half4 pfa, pfb;                                                       \
        pfa[0]=(f16)p0; pfa[1]=(f16)p1; pfa[2]=(f16)p2; pfa[3]=(f16)p3;       \
        pfb[0]=(f16)p4; pfb[1]=(f16)p5; pfb[2]=(f16)p6; pfb[3]=(f16)p7;       \
        accL[qt_] = __builtin_amdgcn_mfma_f32_16x16x16f16(ones, pfa, accL[qt_], 0,0,0); \
        accL[qt_] = __builtin_amdgcn_mfma_f32_16x16x16f16(ones, pfb, accL[qt_], 0,0,0); \
        _Pragma("unroll") for (int ct_ = 0; ct_ < 4; ++ct_) {                 \
            float4v o_ = accO[qt_][ct_];                                      \
            o_ = __builtin_amdgcn_mfma_f32_16x16x16f16(gvf[B][0][ct_], pfa, o_, 0,0,0); \
            accO[qt_][ct_] = __builtin_amdgcn_mfma_f32_16x16x16f16(gvf[B][1][ct_], pfb, o_, 0,0,0); \
        }                                                                     \
    }                                                                         \
} while (0)

    LOADK(0, kt0);
    LOADGV(0, kt0);
    for (int i2 = 0; i2 < 8; ++i2) {
        const int kA = kt0 + i2*64;
        STEP(0, 1, kA + 32);
        STEP(1, 0, kA + 64);   // final prefetch overreads into ws slack: unused
    }

    // publish (m, l) per q-row — accL already holds the full cross-quad sum
    if (kb == 0) {
        #pragma unroll
        for (int qt = 0; qt < 4; ++qt) {
            MLbuf[0][w][qt*16 + m16] = m[qt];
            MLbuf[1][w][qt*16 + m16] = accL[qt][0];
        }
    }
    __syncthreads();

    // global M, L per q-row; scale own partials into the shared frame
    float invL[4];
    #pragma unroll
    for (int qt = 0; qt < 4; ++qt) {
        const int r = qt*16 + m16;
        float M = MLbuf[0][0][r];
        #pragma unroll
        for (int src = 1; src < 8; ++src) M = fmaxf(M, MLbuf[0][src][r]);
        float L = 0.0f;
        #pragma unroll
        for (int src = 0; src < 8; ++src)
            L += MLbuf[1][src][r] * exp2f(MLbuf[0][src][r] - M);
        const float f = exp2f(m[qt] - M);
        #pragma unroll
        for (int ct = 0; ct < 4; ++ct) {
            accO[qt][ct][0] *= f; accO[qt][ct][1] *= f;
            accO[qt][ct][2] *= f; accO[qt][ct][3] *= f;
        }
        invL[qt] = 1.0f / L;
    }

    // 4 staged merge rounds: round rd handles q-tile rd
    for (int rd = 0; rd < 4; ++rd) {
        __syncthreads();
        #pragma unroll
        for (int ct = 0; ct < 4; ++ct)
            ((float4*)&Obuf[w][ct][0])[lane] =
                (float4){accO[rd][ct][0], accO[rd][ct][1], accO[rd][ct][2], accO[rd][ct][3]};
        __syncthreads();
        if (w < 4) {
            float4 s = ((float4*)&Obuf[0][w][0])[lane];
            #pragma unroll
            for (int src = 1; src < 8; ++src) {
                float4 v = ((float4*)&Obuf[src][w][0])[lane];
                s.x += v.x; s.y += v.y; s.z += v.z; s.w += v.w;
            }
            const float iv = invL[rd];
            const int chb = w*16 + kb*4;
            const int row = q0 + rd*16 + m16;
            out[((size_t)n*CC + chb + 0)*HW + row] = s.x * iv;
            out[((size_t)n*CC + chb + 1)*HW + row] = s.y * iv;
            out[((size_t)n*CC + chb + 2)*HW + row] = s.z * iv;
            out[((size_t)n*CC + chb + 3)*HW + row] = s.w * iv;
        }
    }
#undef STEP
#undef LOADGV
#undef LOADK
}

// ---------------------------------------------------------------------------
extern "C" void kernel_launch(void* const* d_in, const int* in_sizes, int n_in,
                              void* d_out, int out_size, void* d_ws, size_t ws_size,
                              hipStream_t stream)
{
    const float* low   = (const float*)d_in[0];
    const float* h0    = (const float*)d_in[1];
    const float* h1    = (const float*)d_in[2];
    const float* Wq    = (const float*)d_in[3];
    const float* bq    = (const float*)d_in[4];
    const float* gq    = (const float*)d_in[5];
    const float* betaq = (const float*)d_in[6];
    const float* Wk    = (const float*)d_in[7];
    const float* bk    = (const float*)d_in[8];
    const float* gk    = (const float*)d_in[9];
    const float* betak = (const float*)d_in[10];
    const float* Wv    = (const float*)d_in[11];
    const float* bv    = (const float*)d_in[12];

    float* wsf = (float*)d_ws;
    float* out = (float*)d_out;

    f16* q  = (f16*)((char*)d_ws + TEN_OFF);
    f16* k  = q + NELEM;
    f16* gv = k + NELEM;

    conv2_kernel<<<dim3(HW/128, NB, 4), 256, 0, stream>>>(
        low, h0, h1, Wq, bq, Wk, bk, Wv, bv, wsf, q, k, gv);

    apply_kernel<<<dim3((int)(NELEM/(256*16)), 2), 256, 0, stream>>>(
        q, k, wsf, gq, betaq, gk, betak);

    attn_kernel<<<dim3(HW/64, NB), 512, 0, stream>>>(q, k, gv, out);
}